// Round 9
// baseline (165.370 us; speedup 1.0000x reference)
//
#include <hip/hip_runtime.h>
#include <stdint.h>

#define N_ANCH 25200
#define NCLS   80
#define KSEL   2048
#define MAXDET 1000
#define CONF_T 0.4f
#define IOU_T  0.45f
#define MAX_WH 7680.0f
#define HBINS  512
#define HBASE  0xBE00u
#define NCAND_MAX 4096
#define NSB    788                  // prep blocks (32 anchors each)
#define NIB    1200                 // img blocks (1024 px-ch each), ride in compact
#define SUPCAP 224                  // max flagged rows held in LDS

// workspace layout (ws is ~267 MB per harness fill; we use < 1 MB)
#define WS_SELSCORE  0              // float  [2048]
#define WS_SELBOX    8192           // float4 [2048]
#define WS_DETCAND   40960          // float  [2048*6]   ends 90112
#define WS_HIST      90112          // uint32 [512]      ends 92160
#define WS_CNT       92160          // uint32 [1]
#define WS_KEYS      92480          // uint32 [25200]    ends 193280
#define WS_CLS       193280         // int32  [25200]    ends 294080
#define WS_MASK      294912         // uint32 MT[64][2048] ends 819200
#define WS_FLAGS     819200         // uint32 flags[64][64] (16 KB) ends 835584
// cand[4096] u64 aliases the first 32 KB of MT: fully consumed by rank_kernel
// BEFORE mask_kernel overwrites MT (stream-ordered).
#define WS_CAND      294912

// ---------------------------------------------------------------- prep kernel
// score only: 8 lanes/anchor, strided class loads, shuffle argmax (exact
// product compare, first-occurrence ties), key + 512-bin global hist.
__global__ void __launch_bounds__(256)
prep_kernel(const float* __restrict__ pred0, uint32_t* __restrict__ keys,
            int* __restrict__ cls, uint32_t* __restrict__ ghist) {
    int tid = threadIdx.x;
    int lane = tid & 63, wave = tid >> 6;
    int g = lane >> 3, l = lane & 7;
    int a = blockIdx.x * 32 + wave * 8 + g;
    if (a >= N_ANCH) return;
    const float* p = pred0 + (size_t)a * 85;
    float obj = p[4];
    float v = -1e30f; int ci = 0;
    #pragma unroll
    for (int k = 0; k < 10; ++k) {
        int c = l + 8 * k;                 // classes 0..79 exactly
        float x = p[5 + c] * obj;          // exact product compare (matches ref)
        if (x > v) { v = x; ci = c; }      // increasing c: > = first occurrence
    }
    #pragma unroll
    for (int m = 1; m < 8; m <<= 1) {
        float ov = __shfl_xor(v, m, 64);
        int   oc = __shfl_xor(ci, m, 64);
        if (ov > v || (ov == v && oc < ci)) { v = ov; ci = oc; }
    }
    if (l == 0) {
        float score = (v > CONF_T) ? v : -1.0f;
        uint32_t bits = __float_as_uint(score);
        uint32_t key = (bits & 0x80000000u) ? ~bits : (bits | 0x80000000u);
        keys[a] = key; cls[a] = ci;
        if (key >= (HBASE << 16)) atomicAdd(&ghist[(key >> 16) - HBASE], 1u);
    }
}

// ------------------------------------------------------------- compact kernel
// blocks [0,25): hist suffix-scan -> lim; per-thread match count; wave
//   shuffle-scan + per-wave totals; ONE global atomicAdd per block; scatter.
// blocks [25,25+NIB): img transform rides along (machine otherwise idle
//   during the 25-block compact stage). x[c][p] = img[p][2-c]/255.
__global__ void __launch_bounds__(256)
compact_kernel(const uint32_t* __restrict__ keys, const uint32_t* __restrict__ ghist,
               uint32_t* __restrict__ cnt, unsigned long long* __restrict__ cand,
               const int* __restrict__ img, float* __restrict__ xout) {
    __shared__ uint32_t h[HBINS];
    __shared__ uint32_t s_lim;
    __shared__ int wtot[4];
    __shared__ int s_base;
    int tid = threadIdx.x;

    if (blockIdx.x >= 25) {                    // ---- img role
        int b = blockIdx.x - 25;
        int i4  = b * 1024 + tid * 4;          // < 1,228,800
        int c   = i4 / 409600;
        int rem = i4 - c * 409600;             // pixel index, multiple of 4
        int ch  = 2 - c;
        const int4* im4 = (const int4*)(img + (size_t)rem * 3);  // 48B-aligned
        int4 v0 = im4[0], v1 = im4[1], v2 = im4[2];
        int p0 = (ch == 0) ? v0.x : (ch == 1) ? v0.y : v0.z;
        int p1 = (ch == 0) ? v0.w : (ch == 1) ? v1.x : v1.y;
        int p2 = (ch == 0) ? v1.z : (ch == 1) ? v1.w : v2.x;
        int p3 = (ch == 0) ? v2.y : (ch == 1) ? v2.z : v2.w;
        float4 o;
        o.x = (float)p0 / 255.0f; o.y = (float)p1 / 255.0f;
        o.z = (float)p2 / 255.0f; o.w = (float)p3 / 255.0f;
        *(float4*)(xout + i4) = o;
        return;
    }

    // ---- compact role
    int lane = tid & 63, wv = tid >> 6;
    h[tid] = ghist[tid]; h[tid + 256] = ghist[tid + 256];
    if (tid == 0) s_lim = (HBASE << 16);
    __syncthreads();
    for (int off = 1; off < HBINS; off <<= 1) {
        uint32_t a0 = h[tid] + ((tid + off < HBINS) ? h[tid + off] : 0u);
        uint32_t a1 = h[tid + 256] + ((tid + 256 + off < HBINS) ? h[tid + 256 + off] : 0u);
        __syncthreads();
        h[tid] = a0; h[tid + 256] = a1;
        __syncthreads();
    }
    for (int b = tid; b < HBINS; b += 256) {
        uint32_t sb  = h[b];
        uint32_t sb1 = (b < HBINS - 1) ? h[b + 1] : 0u;
        if (sb >= KSEL && sb1 < KSEL) s_lim = (uint32_t)(HBASE + b) << 16;
    }
    __syncthreads();
    uint32_t lim = s_lim;

    int i = blockIdx.x * 256 + tid;            // uint4 index (6300 total)
    bool valid = (i < N_ANCH / 4);
    uint32_t ks[4] = {0, 0, 0, 0};
    int cm = 0;
    if (valid) {
        uint4 kk = ((const uint4*)keys)[i];
        ks[0] = kk.x; ks[1] = kk.y; ks[2] = kk.z; ks[3] = kk.w;
        #pragma unroll
        for (int j = 0; j < 4; ++j) cm += (ks[j] >= lim) ? 1 : 0;
    }
    int pre = cm;                               // wave inclusive scan
    #pragma unroll
    for (int o = 1; o < 64; o <<= 1) {
        int v = __shfl_up(pre, o, 64);
        if (lane >= o) pre += v;
    }
    if (lane == 63) wtot[wv] = pre;
    __syncthreads();
    if (tid == 0) {
        int t = 0;
        #pragma unroll
        for (int w = 0; w < 4; ++w) { int x = wtot[w]; wtot[w] = t; t += x; }
        s_base = (t > 0) ? (int)atomicAdd(cnt, (uint32_t)t) : 0;
    }
    __syncthreads();
    int pos = s_base + wtot[wv] + (pre - cm);   // exclusive global position
    if (valid) {
        #pragma unroll
        for (int j = 0; j < 4; ++j) {
            if (ks[j] >= lim) {
                if (pos < NCAND_MAX)
                    cand[pos] = ((unsigned long long)ks[j] << 32)
                              | (uint32_t)(~(uint32_t)(i * 4 + j));
                ++pos;
            }
        }
    }
}

// ---------------------------------------------------------------- rank kernel
// 128 blocks x 256 thr; 32 items/block, 16 lanes/item. rank = #{pack > mine}
// via independent LDS reads; emit at position = rank (total order: idx breaks
// ties -> slots 0..2047 each written exactly once grid-wide).
__global__ void __launch_bounds__(256)
rank_kernel(const uint32_t* __restrict__ cnt, const unsigned long long* __restrict__ cand,
            const float* __restrict__ pred0, const int* __restrict__ cls,
            float* __restrict__ sel_score, float4* __restrict__ selbox,
            float* __restrict__ det_cand) {
    __shared__ unsigned long long s_it[NCAND_MAX];
    __shared__ int s_n;
    int tid = threadIdx.x;
    if (tid == 0) s_n = (int)min(*cnt, (uint32_t)NCAND_MAX);
    __syncthreads();
    int n = s_n;
    int base = blockIdx.x * 32;
    if (base >= n) return;
    for (int i = tid; i < n; i += 256) s_it[i] = cand[i];
    __syncthreads();
    int grp = tid >> 4, s16 = tid & 15;
    #pragma unroll
    for (int o = 0; o < 2; ++o) {
        int it = base + grp + o * 16;
        if (it >= n) break;                     // uniform within 16-lane group
        unsigned long long mine = s_it[it];
        int c = 0;
        for (int t = s16; t < n; t += 16)       // independent LDS reads
            c += (s_it[t] > mine) ? 1 : 0;
        #pragma unroll
        for (int m = 1; m < 16; m <<= 1) c += __shfl_xor(c, m, 64);
        if (s16 == 0 && c < KSEL) {
            uint32_t key = (uint32_t)(mine >> 32);
            int ai = (int)(~(uint32_t)mine);
            uint32_t fb = (key & 0x80000000u) ? (key & 0x7FFFFFFFu) : ~key;
            float score = __uint_as_float(fb);
            const float* p = pred0 + (size_t)ai * 85;
            float x = p[0], y = p[1], w = p[2], hh = p[3];
            float x1 = x - w * 0.5f, y1 = y - hh * 0.5f;
            float x2 = x + w * 0.5f, y2 = y + hh * 0.5f;
            float cf = (float)cls[ai];
            float off = cf * MAX_WH;
            selbox[c] = make_float4(x1 + off, y1 + off, x2 + off, y2 + off);
            float* dc = det_cand + (size_t)c * 6;
            dc[0] = x1; dc[1] = y1; dc[2] = x2; dc[3] = y2; dc[4] = score; dc[5] = cf;
            sel_score[c] = score;
        }
    }
}

// ----------------------------------------------------------------- mask kernel
// 512 blocks: block (wi = blk>>3, rg = blk&7) computes MT[wi][rg*256+tid]
// (coalesced) + flags[wi][word] via one ballot per wave (atomic-free,
// every slot written -> no init needed).
__global__ void __launch_bounds__(256)
mask_kernel(const float4* __restrict__ selbox, uint32_t* __restrict__ MT,
            uint32_t* __restrict__ flags) {
    __shared__ float4 jb[32];
    int tid = threadIdx.x;
    int lane = tid & 63, wv = tid >> 6;
    int wi = blockIdx.x >> 3, rg = blockIdx.x & 7;

    if (tid < 32) jb[tid] = selbox[wi * 32 + tid];
    __syncthreads();
    int row = rg * 256 + tid;
    float4 a = selbox[row];
    float areaA = (a.z - a.x) * (a.w - a.y);
    uint32_t bits = 0;
    #pragma unroll 4
    for (int b = 0; b < 32; ++b) {
        int j = wi * 32 + b;
        if (j > row) {
            float4 q = jb[b];
            float lx = fmaxf(a.x, q.x), ly = fmaxf(a.y, q.y);
            float rx = fminf(a.z, q.z), ry = fminf(a.w, q.w);
            float ww = fmaxf(rx - lx, 0.0f), hh = fmaxf(ry - ly, 0.0f);
            float inter = ww * hh;
            float areaB = (q.z - q.x) * (q.w - q.y);
            float iou = inter / (areaA + areaB - inter + 1e-7f);
            if (iou > IOU_T) bits |= (1u << b);
        }
    }
    MT[(size_t)wi * 2048 + row] = bits;
    unsigned long long bm = __ballot(bits != 0u);   // wave covers 64 rows = 2 words
    if (lane == 0) {
        int wbase = wi * 64 + rg * 8 + wv * 2;
        flags[wbase]     = (uint32_t)bm;
        flags[wbase + 1] = (uint32_t)(bm >> 32);
    }
}

// ------------------------------------------------------------------ nms kernel
// One block. OR-reduce flags -> per-row bitmap f[64]; parallel rowlist build;
// gather flagged rows' M-rows into LDS; one-wave sparse walk; emit + zero-fill.
__global__ void __launch_bounds__(256)
nms_kernel(const uint32_t* __restrict__ MT, const uint32_t* __restrict__ flags,
           const float* __restrict__ sel_score,
           const float* __restrict__ det_cand, float* __restrict__ det) {
    __shared__ uint32_t f[64];
    __shared__ int rowlist[SUPCAP];
    __shared__ uint32_t sup[SUPCAP * 64];      // 56 KB
    __shared__ int s_R;
    int tid = threadIdx.x;

    if (tid < 64) {
        uint32_t fw = 0;
        for (int wi = 0; wi < 64; ++wi)         // coalesced: lanes read contiguous
            fw |= flags[wi * 64 + tid];
        f[tid] = fw;
        int cnt = __popc(fw);
        int pre = cnt;
        for (int o = 1; o < 64; o <<= 1) {
            int v = __shfl_up(pre, o, 64);
            if (tid >= o) pre += v;
        }
        int r = pre - cnt;                      // exclusive prefix
        while (fw) {
            int b = __ffs(fw) - 1; fw &= fw - 1;
            if (r < SUPCAP) rowlist[r] = tid * 32 + b;
            ++r;
        }
        if (tid == 63) s_R = pre;
    }
    __syncthreads();
    int R = s_R;
    bool sparse = (R <= SUPCAP);
    if (sparse) {
        for (int s = tid >> 6; s < R; s += 4)   // 4 rows in flight, 64 lanes each
            sup[s * 64 + (tid & 63)] = MT[(size_t)(tid & 63) * 2048 + rowlist[s]];
    }
    __syncthreads();
    if (tid >= 64) return;

    int lane = tid;
    uint32_t removed = 0;
    #pragma unroll
    for (int b = 0; b < 32; ++b)
        if (!(sel_score[lane * 32 + b] > CONF_T)) removed |= (1u << b);

    if (sparse) {
        int slot = 0;
        for (int w = 0; w < 64; ++w) {
            uint32_t fb = f[w];                 // wave-uniform
            while (fb) {
                int b = __ffs(fb) - 1; fb &= fb - 1;
                uint32_t rv = __shfl((int)removed, w, 64);
                if (!((rv >> b) & 1u))          // row kept -> apply its suppression
                    removed |= sup[slot * 64 + lane];
                ++slot;
            }
        }
    } else {
        for (int c = 0; c < 64; ++c) {          // dense fallback (correctness net)
            const uint4* mb = (const uint4*)(MT + (size_t)lane * 2048 + c * 32);
            uint4 qa[8];
            #pragma unroll
            for (int k = 0; k < 8; ++k) qa[k] = mb[k];
            uint32_t rw[32];
            #pragma unroll
            for (int k = 0; k < 8; ++k) {
                rw[4*k] = qa[k].x; rw[4*k+1] = qa[k].y;
                rw[4*k+2] = qa[k].z; rw[4*k+3] = qa[k].w;
            }
            uint32_t keptmask = 0;
            if (lane == c) {
                uint32_t myrem = removed;
                #pragma unroll
                for (int b = 0; b < 32; ++b)
                    if (!((myrem >> b) & 1u)) { keptmask |= (1u << b); myrem |= rw[b]; }
            }
            keptmask = __shfl(keptmask, c, 64);
            #pragma unroll
            for (int b = 0; b < 32; ++b)
                if ((keptmask >> b) & 1u) removed |= rw[b];
        }
    }

    uint32_t kw = ~removed;
    int cnt2 = __popc(kw);
    int pre = cnt2;
    for (int o = 1; o < 64; o <<= 1) {
        int v = __shfl_up(pre, o, 64);
        if (lane >= o) pre += v;
    }
    int excl = pre - cnt2;
    int total = __shfl(pre, 63, 64);

    int r = excl;
    for (int b = 0; b < 32; ++b) {
        if ((kw >> b) & 1u) {
            if (r < MAXDET) {
                const float* src = det_cand + (size_t)(lane * 32 + b) * 6;
                float* dst = det + (size_t)r * 6;
                for (int j = 0; j < 6; ++j) dst[j] = src[j];
            }
            ++r;
        }
    }
    int start = total < MAXDET ? total : MAXDET;
    for (int z = start + lane; z < MAXDET; z += 64) {
        float* dst = det + (size_t)z * 6;
        for (int j = 0; j < 6; ++j) dst[j] = 0.0f;
    }
}

// ------------------------------------------------------------------ launcher
extern "C" void kernel_launch(void* const* d_in, const int* in_sizes, int n_in,
                              void* d_out, int out_size, void* d_ws, size_t ws_size,
                              hipStream_t stream) {
    const int*   img  = (const int*)d_in[0];
    const float* pred = (const float*)d_in[1];   // (8,25200,85); only batch 0 used
    float* out = (float*)d_out;                  // det[1000*6] then x[1228800]
    char* ws = (char*)d_ws;

    float*    sel_score = (float*)(ws + WS_SELSCORE);
    float4*   selbox    = (float4*)(ws + WS_SELBOX);
    float*    det_cand  = (float*)(ws + WS_DETCAND);
    uint32_t* ghist     = (uint32_t*)(ws + WS_HIST);
    uint32_t* cnt       = (uint32_t*)(ws + WS_CNT);
    uint32_t* keys      = (uint32_t*)(ws + WS_KEYS);
    int*      cls       = (int*)(ws + WS_CLS);
    uint32_t* MT        = (uint32_t*)(ws + WS_MASK);
    uint32_t* flags     = (uint32_t*)(ws + WS_FLAGS);
    unsigned long long* cand = (unsigned long long*)(ws + WS_CAND);  // aliases MT head

    hipMemsetAsync(ghist, 0, 2052, stream);      // hist[512] + cnt
    prep_kernel<<<NSB, 256, 0, stream>>>(pred, keys, cls, ghist);
    compact_kernel<<<25 + NIB, 256, 0, stream>>>(keys, ghist, cnt, cand,
                                                 img, out + MAXDET * 6);
    rank_kernel<<<128, 256, 0, stream>>>(cnt, cand, pred, cls,
                                         sel_score, selbox, det_cand);
    mask_kernel<<<512, 256, 0, stream>>>(selbox, MT, flags);
    nms_kernel<<<1, 256, 0, stream>>>(MT, flags, sel_score, det_cand, out);
}

// Round 11
// 164.027 us; speedup vs baseline: 1.0082x; 1.0082x over previous
//
#include <hip/hip_runtime.h>
#include <stdint.h>

#define N_ANCH 25200
#define NCLS   80
#define KSEL   2048
#define MAXDET 1000
#define CONF_T 0.4f
#define IOU_T  0.45f
#define MAX_WH 7680.0f
#define HBINS  512
#define HBASE  0xBE00u
#define NCAND_MAX 4096
#define NSB    788                  // prep blocks (32 anchors each)
#define NIB    1200                 // img blocks (1024 px-ch each), ride in compact
#define SUPCAP 224                  // max flagged rows held in LDS

// workspace layout (ws is ~267 MB per harness fill; we use < 1 MB)
#define WS_SELSCORE  0              // float  [2048]
#define WS_SELBOX    8192           // float4 [2048]
#define WS_DETCAND   40960          // float  [2048*6]   ends 90112
#define WS_HIST      90112          // uint32 [512]      ends 92160
#define WS_CNT       92160          // uint32 [1]
#define WS_KEYS      92480          // uint32 [25200]    ends 193280
#define WS_CLS       193280         // int32  [25200]    ends 294080
#define WS_MASK      294912         // uint32 MT[64][2048] ends 819200
#define WS_FLAGS     819200         // uint32 flags[64][64] (16 KB) ends 835584
// cand[4096] u64 aliases the first 32 KB of MT: fully consumed by rank_kernel
// BEFORE mask_kernel overwrites MT (stream-ordered).
#define WS_CAND      294912

// ---------------------------------------------------------------- prep kernel
// score only: 8 lanes/anchor, strided class loads, shuffle argmax (exact
// product compare, first-occurrence ties), key + 512-bin global hist.
// NOTE (r10 lesson): ~15K anchors exceed CONF_T (P≈0.6) — the hist-derived
// lim (≈2048th score) is ESSENTIAL, not removable.
__global__ void __launch_bounds__(256)
prep_kernel(const float* __restrict__ pred0, uint32_t* __restrict__ keys,
            int* __restrict__ cls, uint32_t* __restrict__ ghist) {
    int tid = threadIdx.x;
    int lane = tid & 63, wave = tid >> 6;
    int g = lane >> 3, l = lane & 7;
    int a = blockIdx.x * 32 + wave * 8 + g;
    if (a >= N_ANCH) return;
    const float* p = pred0 + (size_t)a * 85;
    float obj = p[4];
    float v = -1e30f; int ci = 0;
    #pragma unroll
    for (int k = 0; k < 10; ++k) {
        int c = l + 8 * k;                 // classes 0..79 exactly
        float x = p[5 + c] * obj;          // exact product compare (matches ref)
        if (x > v) { v = x; ci = c; }      // increasing c: > = first occurrence
    }
    #pragma unroll
    for (int m = 1; m < 8; m <<= 1) {
        float ov = __shfl_xor(v, m, 64);
        int   oc = __shfl_xor(ci, m, 64);
        if (ov > v || (ov == v && oc < ci)) { v = ov; ci = oc; }
    }
    if (l == 0) {
        float score = (v > CONF_T) ? v : -1.0f;
        uint32_t bits = __float_as_uint(score);
        uint32_t key = (bits & 0x80000000u) ? ~bits : (bits | 0x80000000u);
        keys[a] = key; cls[a] = ci;
        if (key >= (HBASE << 16)) atomicAdd(&ghist[(key >> 16) - HBASE], 1u);
    }
}

// ------------------------------------------------------------- compact kernel
// blocks [0,25): hist suffix-scan -> lim; per-thread match count; wave
//   shuffle-scan + per-wave totals; ONE global atomicAdd per block; scatter.
// blocks [25,25+NIB): img transform rides along (machine otherwise idle
//   during the 25-block compact stage). x[c][p] = img[p][2-c]/255.
__global__ void __launch_bounds__(256)
compact_kernel(const uint32_t* __restrict__ keys, const uint32_t* __restrict__ ghist,
               uint32_t* __restrict__ cnt, unsigned long long* __restrict__ cand,
               const int* __restrict__ img, float* __restrict__ xout) {
    __shared__ uint32_t h[HBINS];
    __shared__ uint32_t s_lim;
    __shared__ int wtot[4];
    __shared__ int s_base;
    int tid = threadIdx.x;

    if (blockIdx.x >= 25) {                    // ---- img role
        int b = blockIdx.x - 25;
        int i4  = b * 1024 + tid * 4;          // < 1,228,800
        int c   = i4 / 409600;
        int rem = i4 - c * 409600;             // pixel index, multiple of 4
        int ch  = 2 - c;
        const int4* im4 = (const int4*)(img + (size_t)rem * 3);  // 48B-aligned
        int4 v0 = im4[0], v1 = im4[1], v2 = im4[2];
        int p0 = (ch == 0) ? v0.x : (ch == 1) ? v0.y : v0.z;
        int p1 = (ch == 0) ? v0.w : (ch == 1) ? v1.x : v1.y;
        int p2 = (ch == 0) ? v1.z : (ch == 1) ? v1.w : v2.x;
        int p3 = (ch == 0) ? v2.y : (ch == 1) ? v2.z : v2.w;
        float4 o;
        o.x = (float)p0 / 255.0f; o.y = (float)p1 / 255.0f;
        o.z = (float)p2 / 255.0f; o.w = (float)p3 / 255.0f;
        *(float4*)(xout + i4) = o;
        return;
    }

    // ---- compact role
    int lane = tid & 63, wv = tid >> 6;
    h[tid] = ghist[tid]; h[tid + 256] = ghist[tid + 256];
    if (tid == 0) s_lim = (HBASE << 16);
    __syncthreads();
    for (int off = 1; off < HBINS; off <<= 1) {
        uint32_t a0 = h[tid] + ((tid + off < HBINS) ? h[tid + off] : 0u);
        uint32_t a1 = h[tid + 256] + ((tid + 256 + off < HBINS) ? h[tid + 256 + off] : 0u);
        __syncthreads();
        h[tid] = a0; h[tid + 256] = a1;
        __syncthreads();
    }
    for (int b = tid; b < HBINS; b += 256) {
        uint32_t sb  = h[b];
        uint32_t sb1 = (b < HBINS - 1) ? h[b + 1] : 0u;
        if (sb >= KSEL && sb1 < KSEL) s_lim = (uint32_t)(HBASE + b) << 16;
    }
    __syncthreads();
    uint32_t lim = s_lim;

    int i = blockIdx.x * 256 + tid;            // uint4 index (6300 total)
    bool valid = (i < N_ANCH / 4);
    uint32_t ks[4] = {0, 0, 0, 0};
    int cm = 0;
    if (valid) {
        uint4 kk = ((const uint4*)keys)[i];
        ks[0] = kk.x; ks[1] = kk.y; ks[2] = kk.z; ks[3] = kk.w;
        #pragma unroll
        for (int j = 0; j < 4; ++j) cm += (ks[j] >= lim) ? 1 : 0;
    }
    int pre = cm;                               // wave inclusive scan
    #pragma unroll
    for (int o = 1; o < 64; o <<= 1) {
        int v = __shfl_up(pre, o, 64);
        if (lane >= o) pre += v;
    }
    if (lane == 63) wtot[wv] = pre;
    __syncthreads();
    if (tid == 0) {
        int t = 0;
        #pragma unroll
        for (int w = 0; w < 4; ++w) { int x = wtot[w]; wtot[w] = t; t += x; }
        s_base = (t > 0) ? (int)atomicAdd(cnt, (uint32_t)t) : 0;
    }
    __syncthreads();
    int pos = s_base + wtot[wv] + (pre - cm);   // exclusive global position
    if (valid) {
        #pragma unroll
        for (int j = 0; j < 4; ++j) {
            if (ks[j] >= lim) {
                if (pos < NCAND_MAX)
                    cand[pos] = ((unsigned long long)ks[j] << 32)
                              | (uint32_t)(~(uint32_t)(i * 4 + j));
                ++pos;
            }
        }
    }
}

// ---------------------------------------------------------------- rank kernel
// 128 blocks x 256 thr; 32 items/block, 16 lanes/item. rank = #{pack > mine}
// via independent LDS reads; emit at position = rank (total order: idx breaks
// ties -> slots 0..2047 each written exactly once grid-wide).
__global__ void __launch_bounds__(256)
rank_kernel(const uint32_t* __restrict__ cnt, const unsigned long long* __restrict__ cand,
            const float* __restrict__ pred0, const int* __restrict__ cls,
            float* __restrict__ sel_score, float4* __restrict__ selbox,
            float* __restrict__ det_cand) {
    __shared__ unsigned long long s_it[NCAND_MAX];
    __shared__ int s_n;
    int tid = threadIdx.x;
    if (tid == 0) s_n = (int)min(*cnt, (uint32_t)NCAND_MAX);
    __syncthreads();
    int n = s_n;
    int base = blockIdx.x * 32;
    if (base >= n) return;
    for (int i = tid; i < n; i += 256) s_it[i] = cand[i];
    __syncthreads();
    int grp = tid >> 4, s16 = tid & 15;
    #pragma unroll
    for (int o = 0; o < 2; ++o) {
        int it = base + grp + o * 16;
        if (it >= n) break;                     // uniform within 16-lane group
        unsigned long long mine = s_it[it];
        int c = 0;
        for (int t = s16; t < n; t += 16)       // independent LDS reads
            c += (s_it[t] > mine) ? 1 : 0;
        #pragma unroll
        for (int m = 1; m < 16; m <<= 1) c += __shfl_xor(c, m, 64);
        if (s16 == 0 && c < KSEL) {
            uint32_t key = (uint32_t)(mine >> 32);
            int ai = (int)(~(uint32_t)mine);
            uint32_t fb = (key & 0x80000000u) ? (key & 0x7FFFFFFFu) : ~key;
            float score = __uint_as_float(fb);
            const float* p = pred0 + (size_t)ai * 85;
            float x = p[0], y = p[1], w = p[2], hh = p[3];
            float x1 = x - w * 0.5f, y1 = y - hh * 0.5f;
            float x2 = x + w * 0.5f, y2 = y + hh * 0.5f;
            float cf = (float)cls[ai];
            float off = cf * MAX_WH;
            selbox[c] = make_float4(x1 + off, y1 + off, x2 + off, y2 + off);
            float* dc = det_cand + (size_t)c * 6;
            dc[0] = x1; dc[1] = y1; dc[2] = x2; dc[3] = y2; dc[4] = score; dc[5] = cf;
            sel_score[c] = score;
        }
    }
}

// ----------------------------------------------------------------- mask kernel
// 512 blocks: block (wi = blk>>3, rg = blk&7) computes MT[wi][rg*256+tid]
// (coalesced) + flags[wi][word] via one ballot per wave (atomic-free,
// every slot written -> no init needed).
__global__ void __launch_bounds__(256)
mask_kernel(const float4* __restrict__ selbox, uint32_t* __restrict__ MT,
            uint32_t* __restrict__ flags) {
    __shared__ float4 jb[32];
    int tid = threadIdx.x;
    int lane = tid & 63, wv = tid >> 6;
    int wi = blockIdx.x >> 3, rg = blockIdx.x & 7;

    if (tid < 32) jb[tid] = selbox[wi * 32 + tid];
    __syncthreads();
    int row = rg * 256 + tid;
    float4 a = selbox[row];
    float areaA = (a.z - a.x) * (a.w - a.y);
    uint32_t bits = 0;
    #pragma unroll 4
    for (int b = 0; b < 32; ++b) {
        int j = wi * 32 + b;
        if (j > row) {
            float4 q = jb[b];
            float lx = fmaxf(a.x, q.x), ly = fmaxf(a.y, q.y);
            float rx = fminf(a.z, q.z), ry = fminf(a.w, q.w);
            float ww = fmaxf(rx - lx, 0.0f), hh = fmaxf(ry - ly, 0.0f);
            float inter = ww * hh;
            float areaB = (q.z - q.x) * (q.w - q.y);
            float iou = inter / (areaA + areaB - inter + 1e-7f);
            if (iou > IOU_T) bits |= (1u << b);
        }
    }
    MT[(size_t)wi * 2048 + row] = bits;
    unsigned long long bm = __ballot(bits != 0u);   // wave covers 64 rows = 2 words
    if (lane == 0) {
        int wbase = wi * 64 + rg * 8 + wv * 2;
        flags[wbase]     = (uint32_t)bm;
        flags[wbase + 1] = (uint32_t)(bm >> 32);
    }
}

// ------------------------------------------------------------------ nms kernel
// One block. OR-reduce flags -> per-row bitmap f[64]; parallel rowlist build;
// gather flagged rows' M-rows into LDS; one-wave sparse walk; emit + zero-fill.
__global__ void __launch_bounds__(256)
nms_kernel(const uint32_t* __restrict__ MT, const uint32_t* __restrict__ flags,
           const float* __restrict__ sel_score,
           const float* __restrict__ det_cand, float* __restrict__ det) {
    __shared__ uint32_t f[64];
    __shared__ int rowlist[SUPCAP];
    __shared__ uint32_t sup[SUPCAP * 64];      // 56 KB
    __shared__ int s_R;
    int tid = threadIdx.x;

    if (tid < 64) {
        uint32_t fw = 0;
        for (int wi = 0; wi < 64; ++wi)         // coalesced: lanes read contiguous
            fw |= flags[wi * 64 + tid];
        f[tid] = fw;
        int cnt = __popc(fw);
        int pre = cnt;
        for (int o = 1; o < 64; o <<= 1) {
            int v = __shfl_up(pre, o, 64);
            if (tid >= o) pre += v;
        }
        int r = pre - cnt;                      // exclusive prefix
        while (fw) {
            int b = __ffs(fw) - 1; fw &= fw - 1;
            if (r < SUPCAP) rowlist[r] = tid * 32 + b;
            ++r;
        }
        if (tid == 63) s_R = pre;
    }
    __syncthreads();
    int R = s_R;
    bool sparse = (R <= SUPCAP);
    if (sparse) {
        for (int s = tid >> 6; s < R; s += 4)   // 4 rows in flight, 64 lanes each
            sup[s * 64 + (tid & 63)] = MT[(size_t)(tid & 63) * 2048 + rowlist[s]];
    }
    __syncthreads();
    if (tid >= 64) return;

    int lane = tid;
    uint32_t removed = 0;
    #pragma unroll
    for (int b = 0; b < 32; ++b)
        if (!(sel_score[lane * 32 + b] > CONF_T)) removed |= (1u << b);

    if (sparse) {
        int slot = 0;
        for (int w = 0; w < 64; ++w) {
            uint32_t fb = f[w];                 // wave-uniform
            while (fb) {
                int b = __ffs(fb) - 1; fb &= fb - 1;
                uint32_t rv = __shfl((int)removed, w, 64);
                if (!((rv >> b) & 1u))          // row kept -> apply its suppression
                    removed |= sup[slot * 64 + lane];
                ++slot;
            }
        }
    } else {
        for (int c = 0; c < 64; ++c) {          // dense fallback (correctness net)
            const uint4* mb = (const uint4*)(MT + (size_t)lane * 2048 + c * 32);
            uint4 qa[8];
            #pragma unroll
            for (int k = 0; k < 8; ++k) qa[k] = mb[k];
            uint32_t rw[32];
            #pragma unroll
            for (int k = 0; k < 8; ++k) {
                rw[4*k] = qa[k].x; rw[4*k+1] = qa[k].y;
                rw[4*k+2] = qa[k].z; rw[4*k+3] = qa[k].w;
            }
            uint32_t keptmask = 0;
            if (lane == c) {
                uint32_t myrem = removed;
                #pragma unroll
                for (int b = 0; b < 32; ++b)
                    if (!((myrem >> b) & 1u)) { keptmask |= (1u << b); myrem |= rw[b]; }
            }
            keptmask = __shfl(keptmask, c, 64);
            #pragma unroll
            for (int b = 0; b < 32; ++b)
                if ((keptmask >> b) & 1u) removed |= rw[b];
        }
    }

    uint32_t kw = ~removed;
    int cnt2 = __popc(kw);
    int pre = cnt2;
    for (int o = 1; o < 64; o <<= 1) {
        int v = __shfl_up(pre, o, 64);
        if (lane >= o) pre += v;
    }
    int excl = pre - cnt2;
    int total = __shfl(pre, 63, 64);

    int r = excl;
    for (int b = 0; b < 32; ++b) {
        if ((kw >> b) & 1u) {
            if (r < MAXDET) {
                const float* src = det_cand + (size_t)(lane * 32 + b) * 6;
                float* dst = det + (size_t)r * 6;
                for (int j = 0; j < 6; ++j) dst[j] = src[j];
            }
            ++r;
        }
    }
    int start = total < MAXDET ? total : MAXDET;
    for (int z = start + lane; z < MAXDET; z += 64) {
        float* dst = det + (size_t)z * 6;
        for (int j = 0; j < 6; ++j) dst[j] = 0.0f;
    }
}

// ------------------------------------------------------------------ launcher
extern "C" void kernel_launch(void* const* d_in, const int* in_sizes, int n_in,
                              void* d_out, int out_size, void* d_ws, size_t ws_size,
                              hipStream_t stream) {
    const int*   img  = (const int*)d_in[0];
    const float* pred = (const float*)d_in[1];   // (8,25200,85); only batch 0 used
    float* out = (float*)d_out;                  // det[1000*6] then x[1228800]
    char* ws = (char*)d_ws;

    float*    sel_score = (float*)(ws + WS_SELSCORE);
    float4*   selbox    = (float4*)(ws + WS_SELBOX);
    float*    det_cand  = (float*)(ws + WS_DETCAND);
    uint32_t* ghist     = (uint32_t*)(ws + WS_HIST);
    uint32_t* cnt       = (uint32_t*)(ws + WS_CNT);
    uint32_t* keys      = (uint32_t*)(ws + WS_KEYS);
    int*      cls       = (int*)(ws + WS_CLS);
    uint32_t* MT        = (uint32_t*)(ws + WS_MASK);
    uint32_t* flags     = (uint32_t*)(ws + WS_FLAGS);
    unsigned long long* cand = (unsigned long long*)(ws + WS_CAND);  // aliases MT head

    hipMemsetAsync(ghist, 0, 2052, stream);      // hist[512] + cnt
    prep_kernel<<<NSB, 256, 0, stream>>>(pred, keys, cls, ghist);
    compact_kernel<<<25 + NIB, 256, 0, stream>>>(keys, ghist, cnt, cand,
                                                 img, out + MAXDET * 6);
    rank_kernel<<<128, 256, 0, stream>>>(cnt, cand, pred, cls,
                                         sel_score, selbox, det_cand);
    mask_kernel<<<512, 256, 0, stream>>>(selbox, MT, flags);
    nms_kernel<<<1, 256, 0, stream>>>(MT, flags, sel_score, det_cand, out);
}